// Round 1
// baseline (21824.138 us; speedup 1.0000x reference)
//
#include <hip/hip_runtime.h>
#include <hip/hip_bf16.h>
#include <math.h>

// Problem constants
#define B_  32
#define C_  256
#define H_  64
#define W_  64
#define K_  17
#define HW_ 4096

// Output layout (flat concat of heat, off, var, fw, coords, scores)
#define HEAT_OFF  0
#define OFF_OFF   2228224          // 32*17*64*64
#define VAR_OFF   6684672          // + 32*17*2*64*64
#define FW_OFF    8912896          // + 32*17*64*64
#define COORD_OFF 8912897
#define SCORE_OFF 8913985

// g / sqrt(1 + 1e-5)
#define BN_SCALE 0.9999950000374997f

// ---------------------------------------------------------------------------
// 3x3 SAME conv + BN-scale + bias + ReLU, NCHW fp32.
// Tile: 32 output channels x (8 rows x 64 cols) pixels per block, 256 threads.
// Each thread: 8 co x 8 px register tile. K staged in LDS in chunks of 8 ci.
// ---------------------------------------------------------------------------
__global__ __launch_bounds__(256) void conv3x3_bnrelu(
    const float* __restrict__ in, const float* __restrict__ w,
    const float* __restrict__ gam, const float* __restrict__ bet,
    float* __restrict__ out, int Cin, int Cout) {
  const int nco = Cout >> 5;
  int bz = blockIdx.x;
  const int cot = bz % nco; bz /= nco;
  const int yt = bz & 7;
  const int b  = bz >> 3;
  const int co0 = cot << 5;
  const int y0  = yt << 3;
  const int tid = threadIdx.x;
  const int cgp = tid >> 6;           // 0..3  (co group; uniform per wave)
  const int pg  = tid & 63;
  const int ty  = pg >> 3;            // 0..7
  const int tx  = (pg & 7) << 3;      // 0,8,...,56

  __shared__ float s_in[8][10][68];   // ci, y(+halo), x(+halo, padded to 68)
  __shared__ float s_w[8][9][33];     // ci, ky*3+kx, co (padded 33)

  float acc[8][8];
#pragma unroll
  for (int c = 0; c < 8; ++c)
#pragma unroll
    for (int p = 0; p < 8; ++p) acc[c][p] = 0.f;

  const size_t in_b = (size_t)b * Cin * HW_;

  for (int ci0 = 0; ci0 < Cin; ci0 += 8) {
    // stage input 8 x 10 x 66 (zero-padded borders)
    for (int i = tid; i < 8 * 10 * 66; i += 256) {
      int ci = i / 660; int r = i - ci * 660;
      int yy = r / 66;  int xx = r - yy * 66;
      int gy = y0 + yy - 1;
      int gx = xx - 1;
      float v = 0.f;
      if (gy >= 0 && gy < H_ && gx >= 0 && gx < W_)
        v = in[in_b + (size_t)((ci0 + ci) * HW_ + gy * W_ + gx)];
      s_in[ci][yy][xx] = v;
    }
    // stage weights: [ci][k9][co] for 32 co
    for (int i = tid; i < 32 * 8 * 9; i += 256) {
      int co = i / 72; int r = i - co * 72;
      int ci = r / 9;  int k9 = r - ci * 9;
      s_w[ci][k9][co] = w[((size_t)(co0 + co) * Cin + (ci0 + ci)) * 9 + k9];
    }
    __syncthreads();

#pragma unroll
    for (int ci = 0; ci < 8; ++ci) {
#pragma unroll
      for (int ky = 0; ky < 3; ++ky) {
        float iv[10];
#pragma unroll
        for (int j = 0; j < 10; ++j) iv[j] = s_in[ci][ty + ky][tx + j];
#pragma unroll
        for (int kx = 0; kx < 3; ++kx) {
          float w8[8];
#pragma unroll
          for (int c = 0; c < 8; ++c) w8[c] = s_w[ci][ky * 3 + kx][(cgp << 3) + c];
#pragma unroll
          for (int c = 0; c < 8; ++c)
#pragma unroll
            for (int p = 0; p < 8; ++p)
              acc[c][p] = fmaf(w8[c], iv[kx + p], acc[c][p]);
        }
      }
    }
    __syncthreads();
  }

  // epilogue: BN scale + bias + relu, vectorized store
#pragma unroll
  for (int c = 0; c < 8; ++c) {
    int co = co0 + (cgp << 3) + c;
    float sc = gam[co] * BN_SCALE;
    float bi = bet[co];
    float* op = out + ((size_t)b * Cout + co) * HW_ + (y0 + ty) * W_ + tx;
    float4 v0, v1;
    v0.x = fmaxf(fmaf(acc[c][0], sc, bi), 0.f);
    v0.y = fmaxf(fmaf(acc[c][1], sc, bi), 0.f);
    v0.z = fmaxf(fmaf(acc[c][2], sc, bi), 0.f);
    v0.w = fmaxf(fmaf(acc[c][3], sc, bi), 0.f);
    v1.x = fmaxf(fmaf(acc[c][4], sc, bi), 0.f);
    v1.y = fmaxf(fmaf(acc[c][5], sc, bi), 0.f);
    v1.z = fmaxf(fmaf(acc[c][6], sc, bi), 0.f);
    v1.w = fmaxf(fmaf(acc[c][7], sc, bi), 0.f);
    *(float4*)(op)     = v0;
    *(float4*)(op + 4) = v1;
  }
}

// ---------------------------------------------------------------------------
// 1x1 conv + bias (+ optional softplus). One thread per pixel, CO accs.
// ---------------------------------------------------------------------------
template <int CO, int CIN>
__global__ __launch_bounds__(256) void conv1x1_kernel(
    const float* __restrict__ in, const float* __restrict__ w,
    const float* __restrict__ bias, float* __restrict__ out, int do_softplus) {
  __shared__ float s_w[CO * CIN];
  const int b   = blockIdx.x >> 4;             // 16 blocks of 256 px per image
  const int pix = ((blockIdx.x & 15) << 8) + threadIdx.x;
  for (int i = threadIdx.x; i < CO * CIN; i += 256) s_w[i] = w[i];
  __syncthreads();

  float acc[CO];
#pragma unroll
  for (int co = 0; co < CO; ++co) acc[co] = 0.f;

  const float* ip = in + (size_t)b * CIN * HW_ + pix;
  for (int ci = 0; ci < CIN; ++ci) {
    float v = ip[(size_t)ci * HW_];
#pragma unroll
    for (int co = 0; co < CO; ++co) acc[co] = fmaf(v, s_w[co * CIN + ci], acc[co]);
  }
  float* op = out + (size_t)b * CO * HW_ + pix;
#pragma unroll
  for (int co = 0; co < CO; ++co) {
    float x = acc[co] + bias[co];
    if (do_softplus) x = fmaxf(x, 0.f) + log1pf(expf(-fabsf(x)));
    op[(size_t)co * HW_] = x;
  }
}

// ---------------------------------------------------------------------------
// soft-argmax over each (b,k) 64x64 heatmap: cg (x,y) and score (raw max)
// ---------------------------------------------------------------------------
__global__ __launch_bounds__(256) void soft_argmax_kernel(
    const float* __restrict__ heat, float* __restrict__ cg,
    float* __restrict__ scores) {
  const int bk = blockIdx.x;
  const float* h = heat + (size_t)bk * HW_;
  const int tid = threadIdx.x;
  __shared__ float sred[256];

  float v[16];
  float lmax = -INFINITY;
#pragma unroll
  for (int i = 0; i < 16; ++i) {
    v[i] = h[tid + (i << 8)];
    lmax = fmaxf(lmax, v[i]);
  }
  sred[tid] = lmax; __syncthreads();
  for (int s = 128; s > 0; s >>= 1) {
    if (tid < s) sred[tid] = fmaxf(sred[tid], sred[tid + s]);
    __syncthreads();
  }
  const float m = sred[0];
  __syncthreads();

  float s = 0.f, sx = 0.f, sy = 0.f;
#pragma unroll
  for (int i = 0; i < 16; ++i) {
    int idx = tid + (i << 8);
    float e = expf(v[i] - m);
    s += e;
    sx += e * (float)(idx & 63);
    sy += e * (float)(idx >> 6);
  }
  sred[tid] = s; __syncthreads();
  for (int st = 128; st > 0; st >>= 1) { if (tid < st) sred[tid] += sred[tid + st]; __syncthreads(); }
  const float S = sred[0]; __syncthreads();
  sred[tid] = sx; __syncthreads();
  for (int st = 128; st > 0; st >>= 1) { if (tid < st) sred[tid] += sred[tid + st]; __syncthreads(); }
  const float SX = sred[0]; __syncthreads();
  sred[tid] = sy; __syncthreads();
  for (int st = 128; st > 0; st >>= 1) { if (tid < st) sred[tid] += sred[tid + st]; __syncthreads(); }
  const float SY = sred[0];

  if (tid == 0) {
    cg[bk * 2]     = SX / S;
    cg[bk * 2 + 1] = SY / S;
    scores[bk]     = m;
  }
}

// ---------------------------------------------------------------------------
// local refine (5x5 masked softmax around rounded cg) + blend + bilinear
// offset sampling + final coords; also writes fw.
// ---------------------------------------------------------------------------
__global__ void refine_kernel(
    const float* __restrict__ heat, const float* __restrict__ off,
    const float* __restrict__ cg, const float* __restrict__ alpha_p,
    const float* __restrict__ fusion_p, float* __restrict__ coords_out,
    float* __restrict__ fw_out) {
  const int kp = blockIdx.x * 64 + threadIdx.x;
  const float fw = 1.f / (1.f + expf(-fusion_p[0]));
  if (kp == 0) fw_out[0] = fw;
  if (kp >= B_ * K_) return;

  const float a = 1.f / (1.f + expf(-alpha_p[0]));
  const float* h = heat + (size_t)kp * HW_;
  const float cgx = cg[kp * 2];
  const float cgy = cg[kp * 2 + 1];
  const int px = (int)rintf(fminf(fmaxf(cgx, 0.f), 63.f));
  const int py = (int)rintf(fminf(fmaxf(cgy, 0.f), 63.f));

  float vals[25];
  float m = -INFINITY;
#pragma unroll
  for (int dy = 0; dy < 5; ++dy) {
    int ya = py + dy - 2;
    int yc = min(max(ya, 0), 63);
#pragma unroll
    for (int dx = 0; dx < 5; ++dx) {
      int xa = px + dx - 2;
      int xc = min(max(xa, 0), 63);
      bool inb = (ya >= 0) && (ya < H_) && (xa >= 0) && (xa < W_);
      float val = inb ? h[yc * W_ + xc] : -INFINITY;
      vals[dy * 5 + dx] = val;
      m = fmaxf(m, val);
    }
  }
  float s = 0.f, rx = 0.f, ry = 0.f;
#pragma unroll
  for (int dy = 0; dy < 5; ++dy) {
    int ya = py + dy - 2;
    int yc = min(max(ya, 0), 63);
#pragma unroll
    for (int dx = 0; dx < 5; ++dx) {
      int xa = px + dx - 2;
      int xc = min(max(xa, 0), 63);
      float e = expf(vals[dy * 5 + dx] - m);
      s += e;
      rx += e * (float)xc;
      ry += e * (float)yc;
    }
  }
  rx /= s; ry /= s;

  float cx = a * cgx + (1.f - a) * rx;
  float cy = a * cgy + (1.f - a) * ry;

  // bilinear sample of off (2 channels) at (cx, cy), clipped
  const float ix = fminf(fmaxf(cx, 0.f), 63.f);
  const float iy = fminf(fmaxf(cy, 0.f), 63.f);
  const float x0 = floorf(ix), y0 = floorf(iy);
  const float wx = ix - x0, wy = iy - y0;
  const int x0i = min(max((int)x0, 0), 63);
  const int x1i = min(x0i + 1, 63);
  const int y0i = min(max((int)y0, 0), 63);
  const int y1i = min(y0i + 1, 63);

  float smp[2];
#pragma unroll
  for (int ch = 0; ch < 2; ++ch) {
    const float* oc = off + ((size_t)kp * 2 + ch) * HW_;
    float v00 = oc[y0i * W_ + x0i];
    float v01 = oc[y0i * W_ + x1i];
    float v10 = oc[y1i * W_ + x0i];
    float v11 = oc[y1i * W_ + x1i];
    smp[ch] = (1.f - wy) * ((1.f - wx) * v00 + wx * v01)
            + wy * ((1.f - wx) * v10 + wx * v11);
  }
  cx += fw * smp[0];
  cy += fw * smp[1];
  coords_out[kp * 2]     = cx;
  coords_out[kp * 2 + 1] = cy;
}

// ---------------------------------------------------------------------------
extern "C" void kernel_launch(void* const* d_in, const int* in_sizes, int n_in,
                              void* d_out, int out_size, void* d_ws, size_t ws_size,
                              hipStream_t stream) {
  const float* x    = (const float*)d_in[0];
  const float* w_s1 = (const float*)d_in[1];
  const float* g_s1 = (const float*)d_in[2];
  const float* b_s1 = (const float*)d_in[3];
  const float* w_s2 = (const float*)d_in[4];
  const float* g_s2 = (const float*)d_in[5];
  const float* b_s2 = (const float*)d_in[6];
  const float* w_h1 = (const float*)d_in[7];
  const float* g_h1 = (const float*)d_in[8];
  const float* b_h1 = (const float*)d_in[9];
  const float* w_h2 = (const float*)d_in[10];
  const float* c_h2 = (const float*)d_in[11];
  const float* w_o1 = (const float*)d_in[12];
  const float* g_o1 = (const float*)d_in[13];
  const float* b_o1 = (const float*)d_in[14];
  const float* w_o2 = (const float*)d_in[15];
  const float* c_o2 = (const float*)d_in[16];
  const float* w_v1 = (const float*)d_in[17];
  const float* g_v1 = (const float*)d_in[18];
  const float* b_v1 = (const float*)d_in[19];
  const float* w_v2 = (const float*)d_in[20];
  const float* c_v2 = (const float*)d_in[21];
  const float* alpha  = (const float*)d_in[22];
  const float* fusion = (const float*)d_in[23];

  float* out  = (float*)d_out;
  float* bufA = (float*)d_ws;
  float* bufB = bufA + (size_t)B_ * C_ * HW_;          // +134.2 MB
  float* cgb  = bufB + (size_t)B_ * C_ * HW_;          // +134.2 MB (small)

  dim3 blk(256);
  // s1 = bn_relu(conv3x3(x, w_s1))            -> bufA
  conv3x3_bnrelu<<<2048, blk, 0, stream>>>(x, w_s1, g_s1, b_s1, bufA, 256, 256);
  // s2 = bn_relu(conv3x3(s1, w_s2))           -> bufB
  conv3x3_bnrelu<<<2048, blk, 0, stream>>>(bufA, w_s2, g_s2, b_s2, bufB, 256, 256);
  // h1 = bn_relu(conv3x3(s2, w_h1))           -> bufA
  conv3x3_bnrelu<<<2048, blk, 0, stream>>>(bufB, w_h1, g_h1, b_h1, bufA, 256, 256);
  // heat = conv1x1(h1, w_h2) + c_h2           -> out[HEAT_OFF]
  conv1x1_kernel<17, 256><<<512, blk, 0, stream>>>(bufA, w_h2, c_h2, out + HEAT_OFF, 0);
  // o1 = bn_relu(conv3x3(s2, w_o1))           -> bufA
  conv3x3_bnrelu<<<2048, blk, 0, stream>>>(bufB, w_o1, g_o1, b_o1, bufA, 256, 256);
  // off = conv1x1(o1, w_o2) + c_o2            -> out[OFF_OFF]
  conv1x1_kernel<34, 256><<<512, blk, 0, stream>>>(bufA, w_o2, c_o2, out + OFF_OFF, 0);
  // v1 = bn_relu(conv3x3(s2, w_v1))           -> bufA   (Cout=128)
  conv3x3_bnrelu<<<1024, blk, 0, stream>>>(bufB, w_v1, g_v1, b_v1, bufA, 256, 128);
  // var = softplus(conv1x1(v1, w_v2) + c_v2)  -> out[VAR_OFF]
  conv1x1_kernel<17, 128><<<512, blk, 0, stream>>>(bufA, w_v2, c_v2, out + VAR_OFF, 1);
  // soft-argmax -> cg scratch, scores -> out[SCORE_OFF]
  soft_argmax_kernel<<<544, blk, 0, stream>>>(out + HEAT_OFF, cgb, out + SCORE_OFF);
  // refine + blend + offset sample -> coords, fw
  refine_kernel<<<9, dim3(64), 0, stream>>>(out + HEAT_OFF, out + OFF_OFF, cgb,
                                            alpha, fusion,
                                            out + COORD_OFF, out + FW_OFF);
}

// Round 2
// 3389.009 us; speedup vs baseline: 6.4397x; 6.4397x over previous
//
#include <hip/hip_runtime.h>
#include <hip/hip_bf16.h>
#include <math.h>

// Problem constants
#define B_  32
#define C_  256
#define H_  64
#define W_  64
#define K_  17
#define HW_ 4096

// Output layout (flat concat of heat, off, var, fw, coords, scores)
#define HEAT_OFF  0
#define OFF_OFF   2228224          // 32*17*64*64
#define VAR_OFF   6684672          // + 32*17*2*64*64
#define FW_OFF    8912896          // + 32*17*64*64
#define COORD_OFF 8912897
#define SCORE_OFF 8913985

// g / sqrt(1 + 1e-5)
#define BN_SCALE 0.9999950000374997f

typedef __attribute__((ext_vector_type(8))) short  bf16x8;
typedef __attribute__((ext_vector_type(4))) float  f32x4;

__device__ __forceinline__ unsigned short f2bf(float x) {
  unsigned int u = __float_as_uint(x);
  u = u + 0x7fffu + ((u >> 16) & 1u);
  return (unsigned short)(u >> 16);
}
__device__ __forceinline__ float bf2f(unsigned short h) {
  return __uint_as_float(((unsigned int)h) << 16);
}

// ---------------------------------------------------------------------------
// Workspace layout (bytes)
// ---------------------------------------------------------------------------
#define SZP_ELEMS  35684352ull                    // 32*66*66*256 (one packed tensor)
#define SZP_BYTES  71368704ull
#define XP_HI   0ull
#define XP_LO   71368704ull
#define S1_HI   142737408ull
#define S1_LO   214106112ull
#define S2_HI   285474816ull
#define S2_LO   356843520ull
#define WP_BASE 428212224ull
// per 256-co conv: hi 1179648 B + lo 1179648 B
#define WS1_HI  (WP_BASE)
#define WS1_LO  (WP_BASE + 1179648ull)
#define WS2_HI  (WP_BASE + 2359296ull)
#define WS2_LO  (WP_BASE + 3538944ull)
#define WH1_HI  (WP_BASE + 4718592ull)
#define WH1_LO  (WP_BASE + 5898240ull)
#define WO1_HI  (WP_BASE + 7077888ull)
#define WO1_LO  (WP_BASE + 8257536ull)
#define WV1_HI  (WP_BASE + 9437184ull)
#define WV1_LO  (WP_BASE + 10027008ull)
#define CG_OFF  (WP_BASE + 10616832ull)

// ---------------------------------------------------------------------------
// pack_x: fp32 NCHW -> zero-padded NHWC bf16 hi/lo [32][66][66][256]
// one block per (b, padded row)
// ---------------------------------------------------------------------------
__global__ __launch_bounds__(256) void pack_x(
    const float* __restrict__ x, unsigned short* __restrict__ hi,
    unsigned short* __restrict__ lo) {
  __shared__ float s[128 * 66];
  const int b  = blockIdx.x / 66;
  const int pr = blockIdx.x % 66;
  const size_t obase = ((size_t)(b * 66 + pr) * 66) * 256;
  if (pr == 0 || pr == 65) {
    for (int i = threadIdx.x; i < 66 * 256; i += 256) { hi[obase + i] = 0; lo[obase + i] = 0; }
    return;
  }
  const int y = pr - 1;
  for (int h = 0; h < 2; ++h) {
    __syncthreads();
    for (int i = threadIdx.x; i < 128 * 66; i += 256) {
      int c = i / 66, pc = i % 66;
      int xx = pc - 1;
      float v = (xx >= 0 && xx < 64)
          ? x[((size_t)b * 256 + h * 128 + c) * 4096 + y * 64 + xx] : 0.f;
      s[i] = v;
    }
    __syncthreads();
    for (int i = threadIdx.x; i < 66 * 128; i += 256) {
      int pc = i / 128, c = i % 128;
      float v = s[c * 66 + pc];
      unsigned short hb = f2bf(v);
      size_t o = obase + (size_t)pc * 256 + h * 128 + c;
      hi[o] = hb;
      lo[o] = f2bf(v - bf2f(hb));
    }
  }
}

// ---------------------------------------------------------------------------
// pack_w: OIHW fp32 -> [tap][co][ci] bf16 hi/lo
// ---------------------------------------------------------------------------
__global__ void pack_w(const float* __restrict__ w, unsigned short* __restrict__ hi,
                       unsigned short* __restrict__ lo, int COUT) {
  int i = blockIdx.x * 256 + threadIdx.x;
  int tot = COUT * 256 * 9;
  if (i >= tot) return;
  int co = i / (256 * 9);
  int r  = i - co * 256 * 9;
  int ci = r / 9;
  int k  = r - ci * 9;
  float v = w[i];
  unsigned short h = f2bf(v);
  size_t o = ((size_t)k * COUT + co) * 256 + ci;
  hi[o] = h;
  lo[o] = f2bf(v - bf2f(h));
}

// ---------------------------------------------------------------------------
// zero_border: zero the halo of a packed activation tensor pair
// ---------------------------------------------------------------------------
__global__ void zero_border(unsigned short* __restrict__ hi, unsigned short* __restrict__ lo) {
  int i = blockIdx.x * 256 + threadIdx.x;   // 32 * 260 * 256
  if (i >= 32 * 260 * 256) return;
  int c = i & 255;
  int p = i >> 8;
  int b = p / 260;
  int q = p - b * 260;
  int pr, pc;
  if (q < 66) { pr = 0; pc = q; }
  else if (q < 132) { pr = 65; pc = q - 66; }
  else { int u = q - 132; pr = 1 + (u >> 1); pc = (u & 1) * 65; }
  size_t o = ((size_t)(b * 66 + pr) * 66 + pc) * 256 + c;
  hi[o] = 0; lo[o] = 0;
}

// ---------------------------------------------------------------------------
// MFMA 3x3 conv + BN + ReLU.  Split-bf16 3-pass (hi*hi + lo*hi + hi*lo).
// Block: 128 pixels (2 rows x 64) x 128 cout.  256 threads = 4 waves (2x2).
// Input: padded NHWC bf16 hi/lo.  Weights: [9][COUT][256] bf16 hi/lo.
// OUTMODE 0: write packed padded-NHWC bf16 hi/lo (COUT==256)
// OUTMODE 1: write fp32 NCHW
// ---------------------------------------------------------------------------
#define SIN_BYTES 38016            // 264 px * 144 B  ([hi 64][lo 64][pad 16])
#define BBOFF     38016            // B buffers: hi 128*80, lo 128*80
#define SMEM_SZ   58496

template <int COUT, int OUTMODE>
__global__ __launch_bounds__(256, 2) void conv3x3_mfma(
    const unsigned short* __restrict__ Phi, const unsigned short* __restrict__ Plo,
    const unsigned short* __restrict__ Whi, const unsigned short* __restrict__ Wlo,
    const float* __restrict__ gam, const float* __restrict__ bet,
    unsigned short* __restrict__ Ohi, unsigned short* __restrict__ Olo,
    float* __restrict__ Ofp) {
  constexpr int NB = COUT / 128;
  const int mb   = blockIdx.x % 1024;
  const int nblk = blockIdx.x / 1024;   // 0..NB-1
  const int b     = mb >> 5;
  const int ypair = mb & 31;
  const int Y     = ypair * 2;          // padded input row base (= first out y)

  const int tid  = threadIdx.x;
  const int lane = tid & 63;
  const int wv   = tid >> 6;
  const int l15  = lane & 15;
  const int quad = lane >> 4;
  const int mhalf = (wv & 1) * 64;
  const int nbase = (wv >> 1) * 64;

  __shared__ __align__(16) char smem[SMEM_SZ];

  // A-frag LDS base offsets per m-frag (tap adds (ky*66+kx)*144)
  int aoff[4];
#pragma unroll
  for (int mi = 0; mi < 4; ++mi) {
    int px = mhalf + mi * 16 + l15;
    aoff[mi] = ((px >> 6) * 66 + (px & 63)) * 144 + quad * 16;
  }
  int boff[4];
#pragma unroll
  for (int ni = 0; ni < 4; ++ni)
    boff[ni] = (nbase + ni * 16 + l15) * 80 + quad * 16;

  f32x4 acc[4][4];
#pragma unroll
  for (int mi = 0; mi < 4; ++mi)
#pragma unroll
    for (int ni = 0; ni < 4; ++ni) acc[mi][ni] = (f32x4)0.f;

  const size_t ibase_px = ((size_t)(b * 66 + Y) * 66);   // pixel index of (row Y, col 0)

  uint4 bpref[4], ipref[9];

  // ---- staging helpers ----
  auto loadB = [&](int tt, int cc) {
    int cib = cc * 32;
#pragma unroll
    for (int j = 0; j < 4; ++j) {
      int idx = tid + j * 256;
      int co = idx >> 3, tl = (idx >> 2) & 1, g = idx & 3;
      const unsigned short* src = tl ? Wlo : Whi;
      bpref[j] = *(const uint4*)(src + ((size_t)tt * COUT + nblk * 128 + co) * 256 + cib + g * 8);
    }
  };
  auto writeB = [&]() {
#pragma unroll
    for (int j = 0; j < 4; ++j) {
      int idx = tid + j * 256;
      int co = idx >> 3, tl = (idx >> 2) & 1, g = idx & 3;
      *(uint4*)(smem + BBOFF + tl * 10240 + co * 80 + g * 16) = bpref[j];
    }
  };
  auto loadI = [&](int cc) {
    size_t base = ibase_px * 256 + cc * 32;
#pragma unroll
    for (int j = 0; j < 9; ++j) {
      int idx = tid + j * 256;
      if (idx < 2112) {
        int g = idx & 3, tl = (idx >> 2) & 1, p = idx >> 3;
        const unsigned short* src = tl ? Plo : Phi;
        ipref[j] = *(const uint4*)(src + base + (size_t)p * 256 + g * 8);
      }
    }
  };
  auto writeI = [&]() {
#pragma unroll
    for (int j = 0; j < 9; ++j) {
      int idx = tid + j * 256;
      if (idx < 2112) {
        int g = idx & 3, tl = (idx >> 2) & 1, p = idx >> 3;
        *(uint4*)(smem + p * 144 + tl * 64 + g * 16) = ipref[j];
      }
    }
  };

  // ---- prologue: stage chunk 0 input and B(0,0); prefetch B(0,1) ----
  loadB(0, 0);
  loadI(0);
  writeI();
  writeB();
  loadB(1, 0);
  __syncthreads();

  for (int c8 = 0; c8 < 8; ++c8) {
#pragma unroll
    for (int t = 0; t < 9; ++t) {
      if (t == 7 && c8 < 7) loadI(c8 + 1);

      const int tapadd = ((t / 3) * 66 + (t % 3)) * 144;
      bf16x8 ah[4], al[4], bh[4], bl[4];
#pragma unroll
      for (int mi = 0; mi < 4; ++mi) {
        const char* p = smem + aoff[mi] + tapadd;
        ah[mi] = *(const bf16x8*)p;
        al[mi] = *(const bf16x8*)(p + 64);
      }
#pragma unroll
      for (int ni = 0; ni < 4; ++ni) {
        const char* p = smem + BBOFF + boff[ni];
        bh[ni] = *(const bf16x8*)p;
        bl[ni] = *(const bf16x8*)(p + 10240);
      }
#pragma unroll
      for (int mi = 0; mi < 4; ++mi)
#pragma unroll
        for (int ni = 0; ni < 4; ++ni) {
          acc[mi][ni] = __builtin_amdgcn_mfma_f32_16x16x32_bf16(ah[mi], bh[ni], acc[mi][ni], 0, 0, 0);
          acc[mi][ni] = __builtin_amdgcn_mfma_f32_16x16x32_bf16(al[mi], bh[ni], acc[mi][ni], 0, 0, 0);
          acc[mi][ni] = __builtin_amdgcn_mfma_f32_16x16x32_bf16(ah[mi], bl[ni], acc[mi][ni], 0, 0, 0);
        }

      if (!(c8 == 7 && t == 8)) {
        __syncthreads();
        writeB();                 // B for next slot
        if (t == 8) writeI();     // input for next chunk
        int nt = t + 2, nc = c8;
        if (nt >= 9) { nt -= 9; ++nc; }
        if (nc > 7) { nc = 7; nt = 8; }
        loadB(nt, nc);
        __syncthreads();
      }
    }
  }

  // ---- epilogue: BN + ReLU, write per OUTMODE ----
#pragma unroll
  for (int ni = 0; ni < 4; ++ni) {
    int co = nblk * 128 + nbase + ni * 16 + l15;
    float sc = gam[co] * BN_SCALE;
    float bi = bet[co];
#pragma unroll
    for (int mi = 0; mi < 4; ++mi) {
#pragma unroll
      for (int r = 0; r < 4; ++r) {
        int px = mhalf + mi * 16 + quad * 4 + r;
        int yo = px >> 6, xo = px & 63;
        float v = fmaxf(acc[mi][ni][r] * sc + bi, 0.f);
        if (OUTMODE == 0) {
          size_t o = ((size_t)(b * 66 + Y + yo + 1) * 66 + xo + 1) * 256 + co;
          unsigned short h = f2bf(v);
          Ohi[o] = h;
          Olo[o] = f2bf(v - bf2f(h));
        } else {
          Ofp[((size_t)(b * COUT + co)) * 4096 + (Y + yo) * 64 + xo] = v;
        }
      }
    }
  }
}

// ---------------------------------------------------------------------------
// 1x1 conv + bias (+ optional softplus). One thread per pixel, CO accs.
// ---------------------------------------------------------------------------
template <int CO, int CIN>
__global__ __launch_bounds__(256) void conv1x1_kernel(
    const float* __restrict__ in, const float* __restrict__ w,
    const float* __restrict__ bias, float* __restrict__ out, int do_softplus) {
  __shared__ float s_w[CO * CIN];
  const int b   = blockIdx.x >> 4;
  const int pix = ((blockIdx.x & 15) << 8) + threadIdx.x;
  for (int i = threadIdx.x; i < CO * CIN; i += 256) s_w[i] = w[i];
  __syncthreads();

  float acc[CO];
#pragma unroll
  for (int co = 0; co < CO; ++co) acc[co] = 0.f;

  const float* ip = in + (size_t)b * CIN * HW_ + pix;
  for (int ci = 0; ci < CIN; ++ci) {
    float v = ip[(size_t)ci * HW_];
#pragma unroll
    for (int co = 0; co < CO; ++co) acc[co] = fmaf(v, s_w[co * CIN + ci], acc[co]);
  }
  float* op = out + (size_t)b * CO * HW_ + pix;
#pragma unroll
  for (int co = 0; co < CO; ++co) {
    float x = acc[co] + bias[co];
    if (do_softplus) x = fmaxf(x, 0.f) + log1pf(expf(-fabsf(x)));
    op[(size_t)co * HW_] = x;
  }
}

// ---------------------------------------------------------------------------
// soft-argmax over each (b,k) 64x64 heatmap
// ---------------------------------------------------------------------------
__global__ __launch_bounds__(256) void soft_argmax_kernel(
    const float* __restrict__ heat, float* __restrict__ cg,
    float* __restrict__ scores) {
  const int bk = blockIdx.x;
  const float* h = heat + (size_t)bk * HW_;
  const int tid = threadIdx.x;
  __shared__ float sred[256];

  float v[16];
  float lmax = -INFINITY;
#pragma unroll
  for (int i = 0; i < 16; ++i) {
    v[i] = h[tid + (i << 8)];
    lmax = fmaxf(lmax, v[i]);
  }
  sred[tid] = lmax; __syncthreads();
  for (int s = 128; s > 0; s >>= 1) {
    if (tid < s) sred[tid] = fmaxf(sred[tid], sred[tid + s]);
    __syncthreads();
  }
  const float m = sred[0];
  __syncthreads();

  float s = 0.f, sx = 0.f, sy = 0.f;
#pragma unroll
  for (int i = 0; i < 16; ++i) {
    int idx = tid + (i << 8);
    float e = expf(v[i] - m);
    s += e;
    sx += e * (float)(idx & 63);
    sy += e * (float)(idx >> 6);
  }
  sred[tid] = s; __syncthreads();
  for (int st = 128; st > 0; st >>= 1) { if (tid < st) sred[tid] += sred[tid + st]; __syncthreads(); }
  const float S = sred[0]; __syncthreads();
  sred[tid] = sx; __syncthreads();
  for (int st = 128; st > 0; st >>= 1) { if (tid < st) sred[tid] += sred[tid + st]; __syncthreads(); }
  const float SX = sred[0]; __syncthreads();
  sred[tid] = sy; __syncthreads();
  for (int st = 128; st > 0; st >>= 1) { if (tid < st) sred[tid] += sred[tid + st]; __syncthreads(); }
  const float SY = sred[0];

  if (tid == 0) {
    cg[bk * 2]     = SX / S;
    cg[bk * 2 + 1] = SY / S;
    scores[bk]     = m;
  }
}

// ---------------------------------------------------------------------------
// local refine + blend + bilinear offset sampling + final coords; writes fw.
// ---------------------------------------------------------------------------
__global__ void refine_kernel(
    const float* __restrict__ heat, const float* __restrict__ off,
    const float* __restrict__ cg, const float* __restrict__ alpha_p,
    const float* __restrict__ fusion_p, float* __restrict__ coords_out,
    float* __restrict__ fw_out) {
  const int kp = blockIdx.x * 64 + threadIdx.x;
  const float fw = 1.f / (1.f + expf(-fusion_p[0]));
  if (kp == 0) fw_out[0] = fw;
  if (kp >= B_ * K_) return;

  const float a = 1.f / (1.f + expf(-alpha_p[0]));
  const float* h = heat + (size_t)kp * HW_;
  const float cgx = cg[kp * 2];
  const float cgy = cg[kp * 2 + 1];
  const int px = (int)rintf(fminf(fmaxf(cgx, 0.f), 63.f));
  const int py = (int)rintf(fminf(fmaxf(cgy, 0.f), 63.f));

  float vals[25];
  float m = -INFINITY;
#pragma unroll
  for (int dy = 0; dy < 5; ++dy) {
    int ya = py + dy - 2;
    int yc = min(max(ya, 0), 63);
#pragma unroll
    for (int dx = 0; dx < 5; ++dx) {
      int xa = px + dx - 2;
      int xc = min(max(xa, 0), 63);
      bool inb = (ya >= 0) && (ya < H_) && (xa >= 0) && (xa < W_);
      float val = inb ? h[yc * W_ + xc] : -INFINITY;
      vals[dy * 5 + dx] = val;
      m = fmaxf(m, val);
    }
  }
  float s = 0.f, rx = 0.f, ry = 0.f;
#pragma unroll
  for (int dy = 0; dy < 5; ++dy) {
    int ya = py + dy - 2;
    int yc = min(max(ya, 0), 63);
#pragma unroll
    for (int dx = 0; dx < 5; ++dx) {
      int xa = px + dx - 2;
      int xc = min(max(xa, 0), 63);
      float e = expf(vals[dy * 5 + dx] - m);
      s += e;
      rx += e * (float)xc;
      ry += e * (float)yc;
    }
  }
  rx /= s; ry /= s;

  float cx = a * cgx + (1.f - a) * rx;
  float cy = a * cgy + (1.f - a) * ry;

  const float ix = fminf(fmaxf(cx, 0.f), 63.f);
  const float iy = fminf(fmaxf(cy, 0.f), 63.f);
  const float x0 = floorf(ix), y0 = floorf(iy);
  const float wx = ix - x0, wy = iy - y0;
  const int x0i = min(max((int)x0, 0), 63);
  const int x1i = min(x0i + 1, 63);
  const int y0i = min(max((int)y0, 0), 63);
  const int y1i = min(y0i + 1, 63);

  float smp[2];
#pragma unroll
  for (int ch = 0; ch < 2; ++ch) {
    const float* oc = off + ((size_t)kp * 2 + ch) * HW_;
    float v00 = oc[y0i * W_ + x0i];
    float v01 = oc[y0i * W_ + x1i];
    float v10 = oc[y1i * W_ + x0i];
    float v11 = oc[y1i * W_ + x1i];
    smp[ch] = (1.f - wy) * ((1.f - wx) * v00 + wx * v01)
            + wy * ((1.f - wx) * v10 + wx * v11);
  }
  cx += fw * smp[0];
  cy += fw * smp[1];
  coords_out[kp * 2]     = cx;
  coords_out[kp * 2 + 1] = cy;
}

// ---------------------------------------------------------------------------
extern "C" void kernel_launch(void* const* d_in, const int* in_sizes, int n_in,
                              void* d_out, int out_size, void* d_ws, size_t ws_size,
                              hipStream_t stream) {
  const float* x    = (const float*)d_in[0];
  const float* w_s1 = (const float*)d_in[1];
  const float* g_s1 = (const float*)d_in[2];
  const float* b_s1 = (const float*)d_in[3];
  const float* w_s2 = (const float*)d_in[4];
  const float* g_s2 = (const float*)d_in[5];
  const float* b_s2 = (const float*)d_in[6];
  const float* w_h1 = (const float*)d_in[7];
  const float* g_h1 = (const float*)d_in[8];
  const float* b_h1 = (const float*)d_in[9];
  const float* w_h2 = (const float*)d_in[10];
  const float* c_h2 = (const float*)d_in[11];
  const float* w_o1 = (const float*)d_in[12];
  const float* g_o1 = (const float*)d_in[13];
  const float* b_o1 = (const float*)d_in[14];
  const float* w_o2 = (const float*)d_in[15];
  const float* c_o2 = (const float*)d_in[16];
  const float* w_v1 = (const float*)d_in[17];
  const float* g_v1 = (const float*)d_in[18];
  const float* b_v1 = (const float*)d_in[19];
  const float* w_v2 = (const float*)d_in[20];
  const float* c_v2 = (const float*)d_in[21];
  const float* alpha  = (const float*)d_in[22];
  const float* fusion = (const float*)d_in[23];

  float* out = (float*)d_out;
  char*  ws  = (char*)d_ws;

  unsigned short* xp_hi = (unsigned short*)(ws + XP_HI);
  unsigned short* xp_lo = (unsigned short*)(ws + XP_LO);
  unsigned short* s1_hi = (unsigned short*)(ws + S1_HI);
  unsigned short* s1_lo = (unsigned short*)(ws + S1_LO);
  unsigned short* s2_hi = (unsigned short*)(ws + S2_HI);
  unsigned short* s2_lo = (unsigned short*)(ws + S2_LO);
  unsigned short* ws1_hi = (unsigned short*)(ws + WS1_HI);
  unsigned short* ws1_lo = (unsigned short*)(ws + WS1_LO);
  unsigned short* ws2_hi = (unsigned short*)(ws + WS2_HI);
  unsigned short* ws2_lo = (unsigned short*)(ws + WS2_LO);
  unsigned short* wh1_hi = (unsigned short*)(ws + WH1_HI);
  unsigned short* wh1_lo = (unsigned short*)(ws + WH1_LO);
  unsigned short* wo1_hi = (unsigned short*)(ws + WO1_HI);
  unsigned short* wo1_lo = (unsigned short*)(ws + WO1_LO);
  unsigned short* wv1_hi = (unsigned short*)(ws + WV1_HI);
  unsigned short* wv1_lo = (unsigned short*)(ws + WV1_LO);
  float* F0  = (float*)(ws + 0);             // reuses XP region for h1/o1/v1 fp32
  float* cgb = (float*)(ws + CG_OFF);

  dim3 blk(256);

  // ---- pack inputs & weights, zero halos ----
  pack_x<<<32 * 66, blk, 0, stream>>>(x, xp_hi, xp_lo);
  pack_w<<<256 * 9, blk, 0, stream>>>(w_s1, ws1_hi, ws1_lo, 256);
  pack_w<<<256 * 9, blk, 0, stream>>>(w_s2, ws2_hi, ws2_lo, 256);
  pack_w<<<256 * 9, blk, 0, stream>>>(w_h1, wh1_hi, wh1_lo, 256);
  pack_w<<<256 * 9, blk, 0, stream>>>(w_o1, wo1_hi, wo1_lo, 256);
  pack_w<<<128 * 9, blk, 0, stream>>>(w_v1, wv1_hi, wv1_lo, 128);
  zero_border<<<8320, blk, 0, stream>>>(s1_hi, s1_lo);
  zero_border<<<8320, blk, 0, stream>>>(s2_hi, s2_lo);

  // ---- backbone convs (MFMA) ----
  // s1 = bn_relu(conv(x, w_s1))  : xp -> s1 packed
  conv3x3_mfma<256, 0><<<2048, blk, 0, stream>>>(xp_hi, xp_lo, ws1_hi, ws1_lo,
                                                 g_s1, b_s1, s1_hi, s1_lo, nullptr);
  // s2 = bn_relu(conv(s1, w_s2)) : s1 -> s2 packed
  conv3x3_mfma<256, 0><<<2048, blk, 0, stream>>>(s1_hi, s1_lo, ws2_hi, ws2_lo,
                                                 g_s2, b_s2, s2_hi, s2_lo, nullptr);
  // h1 : s2 -> F0 fp32 NCHW
  conv3x3_mfma<256, 1><<<2048, blk, 0, stream>>>(s2_hi, s2_lo, wh1_hi, wh1_lo,
                                                 g_h1, b_h1, nullptr, nullptr, F0);
  conv1x1_kernel<17, 256><<<512, blk, 0, stream>>>(F0, w_h2, c_h2, out + HEAT_OFF, 0);
  // o1 : s2 -> F0 fp32 NCHW
  conv3x3_mfma<256, 1><<<2048, blk, 0, stream>>>(s2_hi, s2_lo, wo1_hi, wo1_lo,
                                                 g_o1, b_o1, nullptr, nullptr, F0);
  conv1x1_kernel<34, 256><<<512, blk, 0, stream>>>(F0, w_o2, c_o2, out + OFF_OFF, 0);
  // v1 : s2 -> F0 fp32 NCHW (128 ch)
  conv3x3_mfma<128, 1><<<1024, blk, 0, stream>>>(s2_hi, s2_lo, wv1_hi, wv1_lo,
                                                 g_v1, b_v1, nullptr, nullptr, F0);
  conv1x1_kernel<17, 128><<<512, blk, 0, stream>>>(F0, w_v2, c_v2, out + VAR_OFF, 1);

  // ---- heads ----
  soft_argmax_kernel<<<544, blk, 0, stream>>>(out + HEAT_OFF, cgb, out + SCORE_OFF);
  refine_kernel<<<9, dim3(64), 0, stream>>>(out + HEAT_OFF, out + OFF_OFF, cgb,
                                            alpha, fusion,
                                            out + COORD_OFF, out + FW_OFF);
}